// Round 3
// baseline (210.710 us; speedup 1.0000x reference)
//
#include <hip/hip_runtime.h>

// Problem dims
#define NB   4
#define CIN  256
#define MID  64
#define HW   4096
#define O3   192   // f(64)+g(64)+h(64) stacked

// Workspace layout (in floats)
constexpr size_t OFF_FGH   = 0;                                  // [B][192][HW]
constexpr size_t OFF_WEFFT = OFF_FGH   + (size_t)NB * O3 * HW;   // [256][192] W_eff^T (BN folded)
constexpr size_t OFF_BEFF  = OFF_WEFFT + (size_t)CIN * O3;       // [192]
constexpr size_t OFF_VU    = OFF_BEFF  + O3;                     // [B][HW] unnormalized v
constexpr size_t OFF_T     = OFF_VU    + (size_t)NB * HW;        // [B][64]  t = g@v0
constexpr size_t OFF_NSQ   = OFF_T     + (size_t)NB * MID;       // [B]      ||vu||^2
constexpr size_t OFF_FGVU  = OFF_NSQ   + NB;                     // [B][128] f@vu, g@vu
constexpr size_t OFF_SVAL  = OFF_FGVU  + (size_t)NB * 128;       // [B]      s
constexpr size_t OFF_M     = OFF_SVAL  + NB;                     // [B][64][64] M = g h^T
constexpr size_t OFF_W2T   = OFF_M     + (size_t)NB * MID * MID; // [B][64][256] (1/s) (Wv M^T)^T
constexpr size_t WS_FLOATS = OFF_W2T   + (size_t)NB * MID * CIN;

__device__ __forceinline__ float block_reduce_sum_256(float v) {
    #pragma unroll
    for (int off = 32; off > 0; off >>= 1) v += __shfl_down(v, off);
    __shared__ float smem[4];
    if ((threadIdx.x & 63) == 0) smem[threadIdx.x >> 6] = v;
    __syncthreads();
    return smem[0] + smem[1] + smem[2] + smem[3];
}

// K0: fold BN into conv weights; store W_eff transposed [c][o] for coalesced staging.
__global__ void k_weff(const float* __restrict__ Wf, const float* __restrict__ bf,
                       const float* __restrict__ gf, const float* __restrict__ btf,
                       const float* __restrict__ mf, const float* __restrict__ vf,
                       const float* __restrict__ Wg, const float* __restrict__ bg,
                       const float* __restrict__ gg, const float* __restrict__ btg,
                       const float* __restrict__ mg, const float* __restrict__ vg,
                       const float* __restrict__ Wh, const float* __restrict__ bh,
                       float* __restrict__ wefft, float* __restrict__ beff) {
    const int o = blockIdx.x;   // 0..191
    const int c = threadIdx.x;  // 0..255
    float w, sh;
    if (o < 64) {
        float inv = gf[o] * rsqrtf(vf[o] + 1e-5f);
        w  = Wf[o * CIN + c] * inv;
        sh = bf[o] * inv + btf[o] - mf[o] * inv;
    } else if (o < 128) {
        int oo = o - 64;
        float inv = gg[oo] * rsqrtf(vg[oo] + 1e-5f);
        w  = Wg[oo * CIN + c] * inv;
        sh = bg[oo] * inv + btg[oo] - mg[oo] * inv;
    } else {
        int oo = o - 128;
        w  = Wh[oo * CIN + c];
        sh = bh[oo];
    }
    wefft[(size_t)c * O3 + o] = w;
    if (c == 0) beff[o] = sh;
}

// K1: fgh[b][o][n] = relu?( W_eff[o] . x[b][:,n] + beff[o] )   (192x4096 per batch)
// Tile: 128 n x 64 o, K-chunks of 16. 256 thr as 16(tn) x 16(to); 4o x 8n per thread.
__launch_bounds__(256)
__global__ void k_fgh(const float* __restrict__ x, const float* __restrict__ wefft,
                      const float* __restrict__ beff, float* __restrict__ fgh) {
    __shared__ float xs[16][128];
    __shared__ float wsT[16][64];
    const int n0 = blockIdx.x * 128;
    const int o0 = blockIdx.y * 64;
    const int b  = blockIdx.z;
    const float* xb = x + (size_t)b * CIN * HW;
    const int tid = threadIdx.x;
    const int tn = tid & 15;
    const int to = tid >> 4;
    float acc[4][8];
    #pragma unroll
    for (int i = 0; i < 4; ++i)
        #pragma unroll
        for (int j = 0; j < 8; ++j) acc[i][j] = 0.0f;

    for (int c0 = 0; c0 < CIN; c0 += 16) {
        #pragma unroll
        for (int i = 0; i < 2; ++i) {             // stage x chunk: 16x128 floats
            int idx4 = tid + i * 256;
            int r = idx4 >> 5, c4 = idx4 & 31;
            float4 v = *(const float4*)(xb + (size_t)(c0 + r) * HW + n0 + c4 * 4);
            *(float4*)&xs[r][c4 * 4] = v;
        }
        {                                          // stage W chunk: 16x64 floats
            int r = tid >> 4, c4 = tid & 15;
            float4 v = *(const float4*)(wefft + (size_t)(c0 + r) * O3 + o0 + c4 * 4);
            *(float4*)&wsT[r][c4 * 4] = v;
        }
        __syncthreads();
        #pragma unroll
        for (int c = 0; c < 16; ++c) {
            float4 wv4 = *(const float4*)&wsT[c][to * 4];
            float wv[4] = {wv4.x, wv4.y, wv4.z, wv4.w};
            float xv[8];
            #pragma unroll
            for (int j = 0; j < 8; ++j) xv[j] = xs[c][tn + 16 * j];
            #pragma unroll
            for (int i = 0; i < 4; ++i)
                #pragma unroll
                for (int j = 0; j < 8; ++j) acc[i][j] = fmaf(wv[i], xv[j], acc[i][j]);
        }
        __syncthreads();
    }
    #pragma unroll
    for (int i = 0; i < 4; ++i) {
        const int o = o0 + to * 4 + i;
        const float bias = beff[o];
        const bool rl = (o < 128);  // relu on f and g only
        float* dst = fgh + ((size_t)b * O3 + o) * HW + n0;
        #pragma unroll
        for (int j = 0; j < 8; ++j) {
            float v = acc[i][j] + bias;
            if (rl) v = fmaxf(v, 0.0f);
            dst[tn + 16 * j] = v;
        }
    }
}

// K2: t[b][c] = sum_n g[b][c][n] * v0[b][n]
__global__ void k_t(const float* __restrict__ fgh, const float* __restrict__ v0,
                    float* __restrict__ t) {
    const int c = blockIdx.x, b = blockIdx.y;
    const float* g  = fgh + ((size_t)b * O3 + 64 + c) * HW;
    const float* vb = v0 + (size_t)b * HW;
    float a = 0.0f;
    for (int n = threadIdx.x; n < HW; n += 256) a = fmaf(g[n], vb[n], a);
    a = block_reduce_sum_256(a);
    if (threadIdx.x == 0) t[b * MID + c] = a;
}

// K3: vu[b][n] = sum_c f[b][c][n] * t[b][c]; accumulate ||vu||^2 into nsq[b]
__global__ void k_vu(const float* __restrict__ fgh, const float* __restrict__ t,
                     float* __restrict__ vu, float* __restrict__ nsq) {
    const int b = blockIdx.y;
    const int n = blockIdx.x * 256 + threadIdx.x;
    __shared__ float ts[MID];
    if (threadIdx.x < MID) ts[threadIdx.x] = t[b * MID + threadIdx.x];
    __syncthreads();
    const float* fb = fgh + (size_t)b * O3 * HW;
    float a = 0.0f;
    #pragma unroll 8
    for (int c = 0; c < MID; ++c) a = fmaf(fb[(size_t)c * HW + n], ts[c], a);
    vu[(size_t)b * HW + n] = a;
    float sq = block_reduce_sum_256(a * a);
    if (threadIdx.x == 0) atomicAdd(&nsq[b], sq);
}

// K4: fgvu[b][r] = sum_n fgh[b][r][n] * vu[b][n]   (r in 0..127 => f rows then g rows)
__global__ void k_fgv(const float* __restrict__ fgh, const float* __restrict__ vu,
                      float* __restrict__ fgvu) {
    const int r = blockIdx.x, b = blockIdx.y;
    const float* p = fgh + ((size_t)b * O3 + r) * HW;
    const float* v = vu + (size_t)b * HW;
    float a = 0.0f;
    for (int n = threadIdx.x; n < HW; n += 256) a = fmaf(p[n], v[n], a);
    a = block_reduce_sum_256(a);
    if (threadIdx.x == 0) fgvu[b * 128 + r] = a;
}

// K5: s[b] = (f.vu dot g.vu) / ||vu||^2
__global__ void k_s(const float* __restrict__ fgvu, const float* __restrict__ nsq,
                    float* __restrict__ sval) {
    const int b = blockIdx.x, c = threadIdx.x;  // 64 threads
    float a = fgvu[b * 128 + c] * fgvu[b * 128 + 64 + c];
    #pragma unroll
    for (int off = 32; off > 0; off >>= 1) a += __shfl_down(a, off);
    if (c == 0) sval[b] = a / nsq[b];
}

// K6: M[b][cp][cc] += sum_{n in chunk} g[b][cp][n] * h[b][cc][n]   (split-K atomics)
__launch_bounds__(256)
__global__ void k_m(const float* __restrict__ fgh, float* __restrict__ M) {
    __shared__ float gs[64][65];
    __shared__ float hs[64][65];
    const int b = blockIdx.y;
    const int nbase0 = blockIdx.x * 512;
    const int tid = threadIdx.x;
    const int tc = tid & 15, tcp = tid >> 4;
    const float* gb = fgh + ((size_t)b * O3 + 64) * HW;
    const float* hb = fgh + ((size_t)b * O3 + 128) * HW;
    float acc[4][4];
    #pragma unroll
    for (int i = 0; i < 4; ++i)
        #pragma unroll
        for (int j = 0; j < 4; ++j) acc[i][j] = 0.0f;

    for (int nb = 0; nb < 512; nb += 64) {
        const int nbase = nbase0 + nb;
        __syncthreads();
        #pragma unroll
        for (int i = 0; i < 16; ++i) {
            int idx = tid + i * 256;
            int r = idx >> 6, nn = idx & 63;
            gs[r][nn] = gb[(size_t)r * HW + nbase + nn];
            hs[r][nn] = hb[(size_t)r * HW + nbase + nn];
        }
        __syncthreads();
        for (int nn = 0; nn < 64; ++nn) {
            float gv[4], hv[4];
            #pragma unroll
            for (int i = 0; i < 4; ++i) gv[i] = gs[tcp * 4 + i][nn];
            #pragma unroll
            for (int j = 0; j < 4; ++j) hv[j] = hs[tc * 4 + j][nn];
            #pragma unroll
            for (int i = 0; i < 4; ++i)
                #pragma unroll
                for (int j = 0; j < 4; ++j) acc[i][j] = fmaf(gv[i], hv[j], acc[i][j]);
        }
    }
    #pragma unroll
    for (int i = 0; i < 4; ++i)
        #pragma unroll
        for (int j = 0; j < 4; ++j)
            atomicAdd(&M[((size_t)b * MID + tcp * 4 + i) * MID + tc * 4 + j], acc[i][j]);
}

// K7: w2t[b][cp][o] = (1/s[b]) * sum_c Wv[o][c] * M[b][cp][c]
__global__ void k_w2(const float* __restrict__ Wv, const float* __restrict__ M,
                     const float* __restrict__ sval, float* __restrict__ w2t) {
    const int cp = blockIdx.x, b = blockIdx.y, o = threadIdx.x;  // 256 threads
    __shared__ float ms[MID];
    if (threadIdx.x < MID) ms[threadIdx.x] = M[((size_t)b * MID + cp) * MID + threadIdx.x];
    __syncthreads();
    const float inv_s = 1.0f / sval[b];
    float a = 0.0f;
    #pragma unroll 8
    for (int c = 0; c < MID; ++c) a = fmaf(Wv[o * MID + c], ms[c], a);
    w2t[((size_t)b * MID + cp) * CIN + o] = a * inv_s;
}

// K8: out[b][o][n] = x[b][o][n] + bv[o] + sum_cp w2t[b][cp][o] * f[b][cp][n]
__launch_bounds__(256)
__global__ void k_out(const float* __restrict__ x, const float* __restrict__ fgh,
                      const float* __restrict__ w2t, const float* __restrict__ bv,
                      float* __restrict__ out) {
    __shared__ float fs[16][128];
    __shared__ float wsT[16][64];
    const int n0 = blockIdx.x * 128;
    const int o0 = blockIdx.y * 64;
    const int b  = blockIdx.z;
    const float* fb  = fgh + (size_t)b * O3 * HW;   // f rows are 0..63
    const float* w2b = w2t + (size_t)b * MID * CIN;
    const int tid = threadIdx.x;
    const int tn = tid & 15;
    const int to = tid >> 4;
    float acc[4][8];
    #pragma unroll
    for (int i = 0; i < 4; ++i)
        #pragma unroll
        for (int j = 0; j < 8; ++j) acc[i][j] = 0.0f;

    for (int c0 = 0; c0 < MID; c0 += 16) {
        #pragma unroll
        for (int i = 0; i < 2; ++i) {
            int idx4 = tid + i * 256;
            int r = idx4 >> 5, c4 = idx4 & 31;
            float4 v = *(const float4*)(fb + (size_t)(c0 + r) * HW + n0 + c4 * 4);
            *(float4*)&fs[r][c4 * 4] = v;
        }
        {
            int r = tid >> 4, c4 = tid & 15;
            float4 v = *(const float4*)(w2b + (size_t)(c0 + r) * CIN + o0 + c4 * 4);
            *(float4*)&wsT[r][c4 * 4] = v;
        }
        __syncthreads();
        #pragma unroll
        for (int c = 0; c < 16; ++c) {
            float4 wv4 = *(const float4*)&wsT[c][to * 4];
            float wv[4] = {wv4.x, wv4.y, wv4.z, wv4.w};
            float xv[8];
            #pragma unroll
            for (int j = 0; j < 8; ++j) xv[j] = fs[c][tn + 16 * j];
            #pragma unroll
            for (int i = 0; i < 4; ++i)
                #pragma unroll
                for (int j = 0; j < 8; ++j) acc[i][j] = fmaf(wv[i], xv[j], acc[i][j]);
        }
        __syncthreads();
    }
    #pragma unroll
    for (int i = 0; i < 4; ++i) {
        const int o = o0 + to * 4 + i;
        const float bias = bv[o];
        const float* xr = x + ((size_t)b * CIN + o) * HW + n0;
        float* dst = out + ((size_t)b * CIN + o) * HW + n0;
        #pragma unroll
        for (int j = 0; j < 8; ++j)
            dst[tn + 16 * j] = xr[tn + 16 * j] + bias + acc[i][j];
    }
}

extern "C" void kernel_launch(void* const* d_in, const int* in_sizes, int n_in,
                              void* d_out, int out_size, void* d_ws, size_t ws_size,
                              hipStream_t stream) {
    const float* x   = (const float*)d_in[0];
    const float* Wf  = (const float*)d_in[1];
    const float* bf  = (const float*)d_in[2];
    const float* gaf = (const float*)d_in[3];
    const float* bef = (const float*)d_in[4];
    const float* mef = (const float*)d_in[5];
    const float* vaf = (const float*)d_in[6];
    const float* Wg  = (const float*)d_in[7];
    const float* bg  = (const float*)d_in[8];
    const float* gag = (const float*)d_in[9];
    const float* beg = (const float*)d_in[10];
    const float* meg = (const float*)d_in[11];
    const float* vag = (const float*)d_in[12];
    const float* Wh  = (const float*)d_in[13];
    const float* bh  = (const float*)d_in[14];
    const float* Wv  = (const float*)d_in[15];
    const float* bv  = (const float*)d_in[16];
    const float* v0  = (const float*)d_in[17];
    float* out = (float*)d_out;
    float* ws  = (float*)d_ws;

    float* fgh   = ws + OFF_FGH;
    float* wefft = ws + OFF_WEFFT;
    float* beff  = ws + OFF_BEFF;
    float* vu    = ws + OFF_VU;
    float* tvec  = ws + OFF_T;
    float* nsq   = ws + OFF_NSQ;
    float* fgvu  = ws + OFF_FGVU;
    float* sval  = ws + OFF_SVAL;
    float* Mm    = ws + OFF_M;
    float* w2t   = ws + OFF_W2T;

    // zero the atomically-accumulated scratch (nsq, fgvu, sval, M)
    hipMemsetAsync(nsq, 0, (OFF_W2T - OFF_NSQ) * sizeof(float), stream);

    k_weff<<<O3, CIN, 0, stream>>>(Wf, bf, gaf, bef, mef, vaf,
                                   Wg, bg, gag, beg, meg, vag,
                                   Wh, bh, wefft, beff);
    k_fgh<<<dim3(HW / 128, O3 / 64, NB), 256, 0, stream>>>(x, wefft, beff, fgh);
    k_t  <<<dim3(MID, NB), 256, 0, stream>>>(fgh, v0, tvec);
    k_vu <<<dim3(HW / 256, NB), 256, 0, stream>>>(fgh, tvec, vu, nsq);
    k_fgv<<<dim3(128, NB), 256, 0, stream>>>(fgh, vu, fgvu);
    k_s  <<<NB, 64, 0, stream>>>(fgvu, nsq, sval);
    k_m  <<<dim3(HW / 512, NB), 256, 0, stream>>>(fgh, Mm);
    k_w2 <<<dim3(MID, NB), 256, 0, stream>>>(Wv, Mm, sval, w2t);
    k_out<<<dim3(HW / 128, CIN / 64, NB), 256, 0, stream>>>(x, fgh, w2t, bv, out);
}

// Round 5
// 208.350 us; speedup vs baseline: 1.0113x; 1.0113x over previous
//
#include <hip/hip_runtime.h>

// Problem dims
#define NB   4
#define CIN  256
#define MID  64
#define HW   4096
#define O3   192   // f(64)+g(64)+h(64) stacked
#define KB_M 32    // split-K blocks for M partials

typedef __attribute__((ext_vector_type(8))) short bfrag8;   // 8 bf16 (4 VGPR) MFMA operand
typedef __attribute__((ext_vector_type(4))) float facc4;    // MFMA accumulator

// Workspace layout (bytes), total ~36.2 MB
constexpr size_t OFF_FGHT  = 0;           // [B][4096][192] f32
constexpr size_t OFF_FHI   = 12582912;    // [B][4096][64] bf16 (f block, hi)
constexpr size_t OFF_FLO   = 14680064;    // [B][4096][64] bf16 (f block, lo)
constexpr size_t OFF_XHI   = 16777216;    // [B][4096][256] bf16
constexpr size_t OFF_XLO   = 25165824;    // [B][4096][256] bf16
constexpr size_t OFF_WHI   = 33554432;    // [192][256] bf16
constexpr size_t OFF_WLO   = 33652736;    // [192][256] bf16
constexpr size_t OFF_BEFF  = 33751040;    // [192] f32 (padded 1KB)
constexpr size_t OFF_W2HI  = 33752064;    // [B][256][64] bf16
constexpr size_t OFF_W2LO  = 33883136;    // [B][256][64] bf16
constexpr size_t OFF_MPART = 34014208;    // [B][32][64][64] f32
constexpr size_t OFF_T     = 36111360;    // [B][64] f32   (zeroed)
constexpr size_t OFF_FGVU  = 36112384;    // [B][128] f32  (zeroed)
constexpr size_t OFF_NSQ   = 36114432;    // [B] f32       (zeroed)
constexpr size_t OFF_SVAL  = 36114688;    // [B] f32

__device__ __forceinline__ unsigned short f2bf(float f) {
    union { float f; unsigned u; } v; v.f = f;
    unsigned r = v.u + 0x7FFF + ((v.u >> 16) & 1);  // RNE
    return (unsigned short)(r >> 16);
}
__device__ __forceinline__ float bf2f(unsigned short h) {
    union { unsigned u; float f; } v; v.u = ((unsigned)h) << 16;
    return v.f;
}
__device__ __forceinline__ void split_bf(float v, unsigned short& hi, unsigned short& lo) {
    hi = f2bf(v);
    lo = f2bf(v - bf2f(hi));
}

// K0: fold BN into conv weights -> hi/lo bf16 [o][c]; beff f32
__global__ void k_weff(const float* __restrict__ Wf, const float* __restrict__ bf,
                       const float* __restrict__ gf, const float* __restrict__ btf,
                       const float* __restrict__ mf, const float* __restrict__ vf,
                       const float* __restrict__ Wg, const float* __restrict__ bg,
                       const float* __restrict__ gg, const float* __restrict__ btg,
                       const float* __restrict__ mg, const float* __restrict__ vg,
                       const float* __restrict__ Wh, const float* __restrict__ bh,
                       unsigned short* __restrict__ whi, unsigned short* __restrict__ wlo,
                       float* __restrict__ beff) {
    const int o = blockIdx.x;   // 0..191
    const int c = threadIdx.x;  // 0..255
    float w, sh;
    if (o < 64) {
        float inv = gf[o] * rsqrtf(vf[o] + 1e-5f);
        w  = Wf[o * CIN + c] * inv;
        sh = bf[o] * inv + btf[o] - mf[o] * inv;
    } else if (o < 128) {
        int oo = o - 64;
        float inv = gg[oo] * rsqrtf(vg[oo] + 1e-5f);
        w  = Wg[oo * CIN + c] * inv;
        sh = bg[oo] * inv + btg[oo] - mg[oo] * inv;
    } else {
        int oo = o - 128;
        w  = Wh[oo * CIN + c];
        sh = bh[oo];
    }
    unsigned short hi, lo; split_bf(w, hi, lo);
    whi[o * CIN + c] = hi;
    wlo[o * CIN + c] = lo;
    if (c == 0) beff[o] = sh;
}

// K1: x [b][c][n] f32 -> xT hi/lo bf16 [b][n][c] (LDS tile transpose)
__launch_bounds__(256)
__global__ void k_xt(const float* __restrict__ x,
                     unsigned short* __restrict__ xhi, unsigned short* __restrict__ xlo) {
    __shared__ float tl[64][65];   // row=c, col=n; 65-pad -> 2-way max on both phases
    const int n0 = blockIdx.x * 64, c0 = blockIdx.y * 64, b = blockIdx.z;
    const int t = threadIdx.x;
    {   // load: thread handles row c_r, 16-float n-segment
        const int c_r = t >> 2, nseg = t & 3;
        const float* src = x + ((size_t)(b * CIN + c0 + c_r)) * HW + n0 + nseg * 16;
        #pragma unroll
        for (int i = 0; i < 4; ++i) {
            float4 v = *(const float4*)(src + i * 4);
            tl[c_r][nseg * 16 + i * 4 + 0] = v.x;
            tl[c_r][nseg * 16 + i * 4 + 1] = v.y;
            tl[c_r][nseg * 16 + i * 4 + 2] = v.z;
            tl[c_r][nseg * 16 + i * 4 + 3] = v.w;
        }
    }
    __syncthreads();
    {   // gather transposed, split, 16B stores
        const int n_r = t >> 2, cseg = t & 3;
        unsigned short th[16] __attribute__((aligned(16)));
        unsigned short tlo[16] __attribute__((aligned(16)));
        #pragma unroll
        for (int k = 0; k < 16; ++k)
            split_bf(tl[cseg * 16 + k][n_r], th[k], tlo[k]);
        const size_t base = ((size_t)(b * HW + n0 + n_r)) * CIN + c0 + cseg * 16;
        *(bfrag8*)(xhi + base)     = *(const bfrag8*)(th);
        *(bfrag8*)(xhi + base + 8) = *(const bfrag8*)(th + 8);
        *(bfrag8*)(xlo + base)     = *(const bfrag8*)(tlo);
        *(bfrag8*)(xlo + base + 8) = *(const bfrag8*)(tlo + 8);
    }
}

// K2: fghT[b][n][o] f32 = relu?( sum_c xT[n][c] * w[o][c] + beff[o] )  via split-bf16 MFMA
// Also emits f-block (o0==0) as hi/lo bf16 for k_out's MFMA operands.
__launch_bounds__(256)
__global__ void k_fgh(const unsigned short* __restrict__ xhi, const unsigned short* __restrict__ xlo,
                      const unsigned short* __restrict__ whi_, const unsigned short* __restrict__ wlo_,
                      const float* __restrict__ beff, float* __restrict__ fghT,
                      unsigned short* __restrict__ fhi, unsigned short* __restrict__ flo) {
    __shared__ unsigned short xh[64][72], xl[64][72], wh[64][72], wl[64][72];
    const int n0 = blockIdx.x * 64;
    const int o0 = blockIdx.y * 64;     // 0,64,128
    const int b  = blockIdx.z;
    const int tid = threadIdx.x, l = tid & 63, w = tid >> 6;
    const int wo = w >> 1, wn = w & 1;
    const int lr = l & 15, lk = l >> 4;
    facc4 acc[2][2];
    #pragma unroll
    for (int i = 0; i < 2; ++i)
        #pragma unroll
        for (int j = 0; j < 2; ++j) acc[i][j] = (facc4){0.f, 0.f, 0.f, 0.f};

    const size_t xbase = ((size_t)(b * HW + n0)) * CIN;
    const size_t wbase = (size_t)o0 * CIN;

    for (int kc = 0; kc < 4; ++kc) {
        const int c0 = kc * 64;
        #pragma unroll
        for (int i = 0; i < 2; ++i) {
            int ch = tid + i * 256;
            int row = ch >> 3, cs = ch & 7;
            const size_t xsrc = xbase + (size_t)row * CIN + c0 + cs * 8;
            const size_t wsrc = wbase + (size_t)row * CIN + c0 + cs * 8;
            *(bfrag8*)&xh[row][cs * 8] = *(const bfrag8*)(xhi + xsrc);
            *(bfrag8*)&xl[row][cs * 8] = *(const bfrag8*)(xlo + xsrc);
            *(bfrag8*)&wh[row][cs * 8] = *(const bfrag8*)(whi_ + wsrc);
            *(bfrag8*)&wl[row][cs * 8] = *(const bfrag8*)(wlo_ + wsrc);
        }
        __syncthreads();
        #pragma unroll
        for (int ks = 0; ks < 2; ++ks) {
            bfrag8 ah[2], al[2], bh[2], bl[2];
            #pragma unroll
            for (int s = 0; s < 2; ++s) {
                ah[s] = *(const bfrag8*)&xh[wn * 32 + s * 16 + lr][ks * 32 + lk * 8];
                al[s] = *(const bfrag8*)&xl[wn * 32 + s * 16 + lr][ks * 32 + lk * 8];
                bh[s] = *(const bfrag8*)&wh[wo * 32 + s * 16 + lr][ks * 32 + lk * 8];
                bl[s] = *(const bfrag8*)&wl[wo * 32 + s * 16 + lr][ks * 32 + lk * 8];
            }
            #pragma unroll
            for (int sn = 0; sn < 2; ++sn)
                #pragma unroll
                for (int so = 0; so < 2; ++so) {
                    acc[sn][so] = __builtin_amdgcn_mfma_f32_16x16x32_bf16(ah[sn], bh[so], acc[sn][so], 0, 0, 0);
                    acc[sn][so] = __builtin_amdgcn_mfma_f32_16x16x32_bf16(ah[sn], bl[so], acc[sn][so], 0, 0, 0);
                    acc[sn][so] = __builtin_amdgcn_mfma_f32_16x16x32_bf16(al[sn], bh[so], acc[sn][so], 0, 0, 0);
                }
        }
        __syncthreads();
    }
    // epilogue: bias + relu; f32 store + (f block) hi/lo bf16 store
    const bool rl = (o0 < 128);
    #pragma unroll
    for (int so = 0; so < 2; ++so) {
        const int o = o0 + wo * 32 + so * 16 + lr;
        const float bias = beff[o];
        #pragma unroll
        for (int sn = 0; sn < 2; ++sn)
            #pragma unroll
            for (int r = 0; r < 4; ++r) {
                const int n = n0 + wn * 32 + sn * 16 + lk * 4 + r;
                float v = acc[sn][so][r] + bias;
                if (rl) v = fmaxf(v, 0.0f);
                fghT[((size_t)(b * HW) + n) * O3 + o] = v;
                if (o0 == 0) {
                    unsigned short hi, lo; split_bf(v, hi, lo);
                    fhi[((size_t)(b * HW) + n) * MID + o] = hi;
                    flo[((size_t)(b * HW) + n) * MID + o] = lo;
                }
            }
    }
}

// K3: t[b][c] = sum_n g[n][c] * v0[n]
__global__ void k_t(const float* __restrict__ fghT, const float* __restrict__ v0,
                    float* __restrict__ t) {
    __shared__ float red[16][64];
    const int b = blockIdx.y, n0 = blockIdx.x * 512;
    const int tid = threadIdx.x, cq = tid & 15, ng = tid >> 4;
    float a[4] = {0.f, 0.f, 0.f, 0.f};
    for (int it = 0; it < 32; ++it) {
        const int n = n0 + ng + 16 * it;
        float4 gv = *(const float4*)(fghT + ((size_t)(b * HW) + n) * O3 + 64 + cq * 4);
        const float vv = v0[(size_t)b * HW + n];
        a[0] = fmaf(gv.x, vv, a[0]); a[1] = fmaf(gv.y, vv, a[1]);
        a[2] = fmaf(gv.z, vv, a[2]); a[3] = fmaf(gv.w, vv, a[3]);
    }
    #pragma unroll
    for (int i = 0; i < 4; ++i) red[ng][cq * 4 + i] = a[i];
    __syncthreads();
    if (tid < 64) {
        float s = 0.f;
        #pragma unroll
        for (int g = 0; g < 16; ++g) s += red[g][tid];
        atomicAdd(&t[b * MID + tid], s);
    }
}

// K4 (fused): vu[n] = sum_c f[n][c] t[c] (kept in LDS); nsq += |vu|^2;
//             fgvu[r] += sum_n fghT[n][r] * vu[n]  (r = 0..127: f rows then g rows)
__launch_bounds__(256)
__global__ void k_vfg(const float* __restrict__ fghT, const float* __restrict__ t,
                      float* __restrict__ fgvu, float* __restrict__ nsq) {
    __shared__ float ts[64];
    __shared__ float vuls[512];
    __shared__ float red2[8][128];
    __shared__ float rs[4];
    const int b = blockIdx.y, n0 = blockIdx.x * 512;
    const int tid = threadIdx.x;
    if (tid < 64) ts[tid] = t[b * MID + tid];
    __syncthreads();
    // phase 1: vu for this block's 512 n (4 lanes cooperate per n)
    const int nl = tid >> 2, q = tid & 3;
    float mynsq = 0.f;
    for (int ps = 0; ps < 8; ++ps) {
        const int n = n0 + ps * 64 + nl;
        const float* p = fghT + ((size_t)(b * HW) + n) * O3 + q * 16;
        float a = 0.f;
        #pragma unroll
        for (int u = 0; u < 4; ++u) {
            float4 fv = *(const float4*)(p + u * 4);
            a = fmaf(fv.x, ts[q * 16 + u * 4 + 0], a);
            a = fmaf(fv.y, ts[q * 16 + u * 4 + 1], a);
            a = fmaf(fv.z, ts[q * 16 + u * 4 + 2], a);
            a = fmaf(fv.w, ts[q * 16 + u * 4 + 3], a);
        }
        a += __shfl_xor(a, 1);
        a += __shfl_xor(a, 2);
        if (q == 0) { vuls[ps * 64 + nl] = a; mynsq += a * a; }
    }
    {   // nsq reduce (barrier also publishes vuls)
        float s = mynsq;
        #pragma unroll
        for (int off = 32; off > 0; off >>= 1) s += __shfl_down(s, off);
        if ((tid & 63) == 0) rs[tid >> 6] = s;
        __syncthreads();
        if (tid == 0) atomicAdd(&nsq[b], rs[0] + rs[1] + rs[2] + rs[3]);
    }
    // phase 2: fgvu partials
    const int rq = tid & 31, ng2 = tid >> 5;
    float a2[4] = {0.f, 0.f, 0.f, 0.f};
    for (int it = 0; it < 64; ++it) {
        const int ni = ng2 + 8 * it;
        float4 fv = *(const float4*)(fghT + ((size_t)(b * HW) + n0 + ni) * O3 + rq * 4);
        const float vv = vuls[ni];
        a2[0] = fmaf(fv.x, vv, a2[0]); a2[1] = fmaf(fv.y, vv, a2[1]);
        a2[2] = fmaf(fv.z, vv, a2[2]); a2[3] = fmaf(fv.w, vv, a2[3]);
    }
    #pragma unroll
    for (int i = 0; i < 4; ++i) red2[ng2][rq * 4 + i] = a2[i];
    __syncthreads();
    if (tid < 128) {
        float s = 0.f;
        #pragma unroll
        for (int g = 0; g < 8; ++g) s += red2[g][tid];
        atomicAdd(&fgvu[b * 128 + tid], s);
    }
}

// K5: s[b] = (f.vu dot g.vu) / ||vu||^2
__global__ void k_s(const float* __restrict__ fgvu, const float* __restrict__ nsq,
                    float* __restrict__ sval) {
    const int b = blockIdx.x, c = threadIdx.x;  // 64 threads
    float a = fgvu[b * 128 + c] * fgvu[b * 128 + 64 + c];
    #pragma unroll
    for (int off = 32; off > 0; off >>= 1) a += __shfl_down(a, off);
    if (c == 0) sval[b] = a / nsq[b];
}

// K6: split-K partials of M[cp][cc] = sum_n g[n][cp] h[n][cc]   (f32)
__launch_bounds__(256)
__global__ void k_m(const float* __restrict__ fghT, float* __restrict__ mpart) {
    __shared__ float ghls[64][128];   // row=nn; cols 0..63 g, 64..127 h
    const int b = blockIdx.y, kb = blockIdx.x;
    const int tid = threadIdx.x, tc = tid & 15, tcp = tid >> 4;
    float acc[4][4];
    #pragma unroll
    for (int i = 0; i < 4; ++i)
        #pragma unroll
        for (int j = 0; j < 4; ++j) acc[i][j] = 0.f;
    for (int st = 0; st < 2; ++st) {
        const int nb = kb * 128 + st * 64;
        __syncthreads();
        #pragma unroll
        for (int i = 0; i < 8; ++i) {
            int ch = tid + i * 256;
            int row = ch >> 5, cs = ch & 31;
            *(float4*)&ghls[row][cs * 4] =
                *(const float4*)(fghT + ((size_t)(b * HW) + nb + row) * O3 + 64 + cs * 4);
        }
        __syncthreads();
        for (int nn = 0; nn < 64; ++nn) {
            float gv[4], hv[4];
            #pragma unroll
            for (int i = 0; i < 4; ++i) gv[i] = ghls[nn][tcp * 4 + i];
            #pragma unroll
            for (int j = 0; j < 4; ++j) hv[j] = ghls[nn][64 + tc * 4 + j];
            #pragma unroll
            for (int i = 0; i < 4; ++i)
                #pragma unroll
                for (int j = 0; j < 4; ++j) acc[i][j] = fmaf(gv[i], hv[j], acc[i][j]);
        }
    }
    #pragma unroll
    for (int i = 0; i < 4; ++i) {
        float4 v = make_float4(acc[i][0], acc[i][1], acc[i][2], acc[i][3]);
        *(float4*)(mpart + (((size_t)(b * KB_M + kb) * 64 + tcp * 4 + i) * 64 + tc * 4)) = v;
    }
}

// K7: reduce mpart -> M; w2[b][o][cp] = (1/s) sum_c Wv[o][c] M[cp][c]  (hi/lo bf16)
__launch_bounds__(256)
__global__ void k_w2(const float* __restrict__ Wv, const float* __restrict__ mpart,
                     const float* __restrict__ sval,
                     unsigned short* __restrict__ w2hi, unsigned short* __restrict__ w2lo) {
    __shared__ float M[64][64];
    const int b = blockIdx.x, tid = threadIdx.x;
    for (int k = 0; k < 16; ++k) {
        const int e = tid + k * 256;
        float s = 0.f;
        #pragma unroll 8
        for (int kb = 0; kb < KB_M; ++kb)
            s += mpart[(size_t)(b * KB_M + kb) * 4096 + e];
        M[e >> 6][e & 63] = s;
    }
    __syncthreads();
    const float inv_s = 1.0f / sval[b];
    const int o = tid;
    float wv[64];
    #pragma unroll
    for (int c = 0; c < 64; ++c) wv[c] = Wv[o * MID + c];
    for (int cg = 0; cg < 8; ++cg) {
        unsigned short rh[8] __attribute__((aligned(16)));
        unsigned short rl[8] __attribute__((aligned(16)));
        #pragma unroll
        for (int j = 0; j < 8; ++j) {
            const int cp = cg * 8 + j;
            float a = 0.f;
            #pragma unroll
            for (int c = 0; c < 64; ++c) a = fmaf(wv[c], M[cp][c], a);
            split_bf(a * inv_s, rh[j], rl[j]);
        }
        const size_t base = ((size_t)(b * CIN) + o) * MID + cg * 8;
        *(bfrag8*)(w2hi + base) = *(const bfrag8*)rh;
        *(bfrag8*)(w2lo + base) = *(const bfrag8*)rl;
    }
}

// K8: out[b][o][n] = x + bv[o] + sum_cp w2[o][cp] f[n][cp]   via split-bf16 MFMA, D[o][n]
__launch_bounds__(256)
__global__ void k_out(const float* __restrict__ x,
                      const unsigned short* __restrict__ fhi, const unsigned short* __restrict__ flo,
                      const unsigned short* __restrict__ w2hi, const unsigned short* __restrict__ w2lo,
                      const float* __restrict__ bv, float* __restrict__ out) {
    __shared__ unsigned short fh[64][72], fl[64][72], wh[64][72], wl[64][72];
    const int n0 = blockIdx.x * 64;
    const int o0 = blockIdx.y * 64;
    const int b  = blockIdx.z;
    const int tid = threadIdx.x, l = tid & 63, w = tid >> 6;
    const int wo = w >> 1, wn = w & 1;
    const int lr = l & 15, lk = l >> 4;
    #pragma unroll
    for (int i = 0; i < 2; ++i) {
        int ch = tid + i * 256;
        int row = ch >> 3, cs = ch & 7;
        const size_t fsrc = ((size_t)(b * HW) + n0 + row) * MID + cs * 8;
        const size_t wsrc = ((size_t)(b * CIN) + o0 + row) * MID + cs * 8;
        *(bfrag8*)&fh[row][cs * 8] = *(const bfrag8*)(fhi + fsrc);
        *(bfrag8*)&fl[row][cs * 8] = *(const bfrag8*)(flo + fsrc);
        *(bfrag8*)&wh[row][cs * 8] = *(const bfrag8*)(w2hi + wsrc);
        *(bfrag8*)&wl[row][cs * 8] = *(const bfrag8*)(w2lo + wsrc);
    }
    __syncthreads();
    facc4 acc[2][2];   // [so][sn]
    #pragma unroll
    for (int i = 0; i < 2; ++i)
        #pragma unroll
        for (int j = 0; j < 2; ++j) acc[i][j] = (facc4){0.f, 0.f, 0.f, 0.f};
    #pragma unroll
    for (int ks = 0; ks < 2; ++ks) {
        bfrag8 ah[2], al[2], bh[2], bl[2];
        #pragma unroll
        for (int s = 0; s < 2; ++s) {
            ah[s] = *(const bfrag8*)&wh[wo * 32 + s * 16 + lr][ks * 32 + lk * 8];
            al[s] = *(const bfrag8*)&wl[wo * 32 + s * 16 + lr][ks * 32 + lk * 8];
            bh[s] = *(const bfrag8*)&fh[wn * 32 + s * 16 + lr][ks * 32 + lk * 8];
            bl[s] = *(const bfrag8*)&fl[wn * 32 + s * 16 + lr][ks * 32 + lk * 8];
        }
        #pragma unroll
        for (int so = 0; so < 2; ++so)
            #pragma unroll
            for (int sn = 0; sn < 2; ++sn) {
                acc[so][sn] = __builtin_amdgcn_mfma_f32_16x16x32_bf16(ah[so], bh[sn], acc[so][sn], 0, 0, 0);
                acc[so][sn] = __builtin_amdgcn_mfma_f32_16x16x32_bf16(ah[so], bl[sn], acc[so][sn], 0, 0, 0);
                acc[so][sn] = __builtin_amdgcn_mfma_f32_16x16x32_bf16(al[so], bh[sn], acc[so][sn], 0, 0, 0);
            }
    }
    #pragma unroll
    for (int so = 0; so < 2; ++so)
        #pragma unroll
        for (int r = 0; r < 4; ++r) {
            const int o = o0 + wo * 32 + so * 16 + lk * 4 + r;
            const float bias = bv[o];
            #pragma unroll
            for (int sn = 0; sn < 2; ++sn) {
                const int n = n0 + wn * 32 + sn * 16 + lr;
                const size_t idx = ((size_t)(b * CIN) + o) * HW + n;
                out[idx] = x[idx] + bias + acc[so][sn][r];
            }
        }
}

extern "C" void kernel_launch(void* const* d_in, const int* in_sizes, int n_in,
                              void* d_out, int out_size, void* d_ws, size_t ws_size,
                              hipStream_t stream) {
    const float* x   = (const float*)d_in[0];
    const float* Wf  = (const float*)d_in[1];
    const float* bf  = (const float*)d_in[2];
    const float* gaf = (const float*)d_in[3];
    const float* bef = (const float*)d_in[4];
    const float* mef = (const float*)d_in[5];
    const float* vaf = (const float*)d_in[6];
    const float* Wg  = (const float*)d_in[7];
    const float* bg  = (const float*)d_in[8];
    const float* gag = (const float*)d_in[9];
    const float* beg = (const float*)d_in[10];
    const float* meg = (const float*)d_in[11];
    const float* vag = (const float*)d_in[12];
    const float* Wh  = (const float*)d_in[13];
    const float* bh  = (const float*)d_in[14];
    const float* Wv  = (const float*)d_in[15];
    const float* bv  = (const float*)d_in[16];
    const float* v0  = (const float*)d_in[17];
    float* out = (float*)d_out;
    char* ws = (char*)d_ws;

    float*          fghT = (float*)(ws + OFF_FGHT);
    unsigned short* fhi  = (unsigned short*)(ws + OFF_FHI);
    unsigned short* flo  = (unsigned short*)(ws + OFF_FLO);
    unsigned short* xhi  = (unsigned short*)(ws + OFF_XHI);
    unsigned short* xlo  = (unsigned short*)(ws + OFF_XLO);
    unsigned short* whi  = (unsigned short*)(ws + OFF_WHI);
    unsigned short* wlo  = (unsigned short*)(ws + OFF_WLO);
    float*          beff = (float*)(ws + OFF_BEFF);
    unsigned short* w2hi = (unsigned short*)(ws + OFF_W2HI);
    unsigned short* w2lo = (unsigned short*)(ws + OFF_W2LO);
    float*          mpart= (float*)(ws + OFF_MPART);
    float*          tvec = (float*)(ws + OFF_T);
    float*          fgvu = (float*)(ws + OFF_FGVU);
    float*          nsq  = (float*)(ws + OFF_NSQ);
    float*          sval = (float*)(ws + OFF_SVAL);

    // zero atomically-accumulated scratch (t, fgvu, nsq)
    hipMemsetAsync(tvec, 0, 3328, stream);

    k_weff<<<O3, CIN, 0, stream>>>(Wf, bf, gaf, bef, mef, vaf,
                                   Wg, bg, gag, beg, meg, vag,
                                   Wh, bh, whi, wlo, beff);
    k_xt  <<<dim3(HW / 64, CIN / 64, NB), 256, 0, stream>>>(x, xhi, xlo);
    k_fgh <<<dim3(HW / 64, O3 / 64, NB), 256, 0, stream>>>(xhi, xlo, whi, wlo, beff, fghT, fhi, flo);
    k_t   <<<dim3(8, NB), 256, 0, stream>>>(fghT, v0, tvec);
    k_m   <<<dim3(KB_M, NB), 256, 0, stream>>>(fghT, mpart);
    k_vfg <<<dim3(8, NB), 256, 0, stream>>>(fghT, tvec, fgvu, nsq);
    k_s   <<<NB, 64, 0, stream>>>(fgvu, nsq, sval);
    k_w2  <<<NB, CIN, 0, stream>>>(Wv, mpart, sval, w2hi, w2lo);
    k_out <<<dim3(HW / 64, CIN / 64, NB), 256, 0, stream>>>(x, fhi, flo, w2hi, w2lo, bv, out);
}

// Round 6
// 149.878 us; speedup vs baseline: 1.4059x; 1.3901x over previous
//
#include <hip/hip_runtime.h>

// Problem dims
#define NB   4
#define CIN  256
#define MID  64
#define HW   4096
#define O3   192   // f(64)+g(64)+h(64) stacked
#define KB_M 32    // split-K blocks for M partials

typedef __attribute__((ext_vector_type(8))) short bfrag8;   // 8 bf16 (4 VGPR) MFMA operand
typedef __attribute__((ext_vector_type(4))) float facc4;    // MFMA accumulator

// Workspace layout (bytes), total ~36.2 MB
constexpr size_t OFF_FGHT  = 0;           // [B][4096][192] f32
constexpr size_t OFF_FHI   = 12582912;    // [B][4096][64] bf16 (f block, hi)
constexpr size_t OFF_FLO   = 14680064;    // [B][4096][64] bf16 (f block, lo)
constexpr size_t OFF_XHI   = 16777216;    // [B][4096][256] bf16
constexpr size_t OFF_XLO   = 25165824;    // [B][4096][256] bf16
constexpr size_t OFF_WHI   = 33554432;    // [192][256] bf16
constexpr size_t OFF_WLO   = 33652736;    // [192][256] bf16
constexpr size_t OFF_BEFF  = 33751040;    // [192] f32 (padded 1KB)
constexpr size_t OFF_W2HI  = 33752064;    // [B][256][64] bf16
constexpr size_t OFF_W2LO  = 33883136;    // [B][256][64] bf16
constexpr size_t OFF_MPART = 34014208;    // [B][32][64][64] f32
constexpr size_t OFF_T     = 36111360;    // [B][64] f32   (zeroed)
constexpr size_t OFF_FGVU  = 36112384;    // [B][128] f32  (zeroed)
constexpr size_t OFF_NSQ   = 36114432;    // [B] f32       (zeroed)
constexpr size_t OFF_SVAL  = 36114688;    // [B] f32

__device__ __forceinline__ unsigned short f2bf(float f) {
    union { float f; unsigned u; } v; v.f = f;
    unsigned r = v.u + 0x7FFF + ((v.u >> 16) & 1);  // RNE
    return (unsigned short)(r >> 16);
}
__device__ __forceinline__ float bf2f(unsigned short h) {
    union { unsigned u; float f; } v; v.u = ((unsigned)h) << 16;
    return v.f;
}
__device__ __forceinline__ void split_bf(float v, unsigned short& hi, unsigned short& lo) {
    hi = f2bf(v);
    lo = f2bf(v - bf2f(hi));
}

// K0: fold BN into conv weights -> hi/lo bf16 [o][c]; beff f32
__global__ void k_weff(const float* __restrict__ Wf, const float* __restrict__ bf,
                       const float* __restrict__ gf, const float* __restrict__ btf,
                       const float* __restrict__ mf, const float* __restrict__ vf,
                       const float* __restrict__ Wg, const float* __restrict__ bg,
                       const float* __restrict__ gg, const float* __restrict__ btg,
                       const float* __restrict__ mg, const float* __restrict__ vg,
                       const float* __restrict__ Wh, const float* __restrict__ bh,
                       unsigned short* __restrict__ whi, unsigned short* __restrict__ wlo,
                       float* __restrict__ beff) {
    const int o = blockIdx.x;   // 0..191
    const int c = threadIdx.x;  // 0..255
    float w, sh;
    if (o < 64) {
        float inv = gf[o] * rsqrtf(vf[o] + 1e-5f);
        w  = Wf[o * CIN + c] * inv;
        sh = bf[o] * inv + btf[o] - mf[o] * inv;
    } else if (o < 128) {
        int oo = o - 64;
        float inv = gg[oo] * rsqrtf(vg[oo] + 1e-5f);
        w  = Wg[oo * CIN + c] * inv;
        sh = bg[oo] * inv + btg[oo] - mg[oo] * inv;
    } else {
        int oo = o - 128;
        w  = Wh[oo * CIN + c];
        sh = bh[oo];
    }
    unsigned short hi, lo; split_bf(w, hi, lo);
    whi[o * CIN + c] = hi;
    wlo[o * CIN + c] = lo;
    if (c == 0) beff[o] = sh;
}

// K1: x [b][c][n] f32 -> xT hi/lo bf16 [b][n][c] (LDS tile transpose)
__launch_bounds__(256)
__global__ void k_xt(const float* __restrict__ x,
                     unsigned short* __restrict__ xhi, unsigned short* __restrict__ xlo) {
    __shared__ float tl[64][65];   // row=c, col=n
    const int n0 = blockIdx.x * 64, c0 = blockIdx.y * 64, b = blockIdx.z;
    const int t = threadIdx.x;
    {   // load: thread handles row c_r, 16-float n-segment
        const int c_r = t >> 2, nseg = t & 3;
        const float* src = x + ((size_t)(b * CIN + c0 + c_r)) * HW + n0 + nseg * 16;
        #pragma unroll
        for (int i = 0; i < 4; ++i) {
            float4 v = *(const float4*)(src + i * 4);
            tl[c_r][nseg * 16 + i * 4 + 0] = v.x;
            tl[c_r][nseg * 16 + i * 4 + 1] = v.y;
            tl[c_r][nseg * 16 + i * 4 + 2] = v.z;
            tl[c_r][nseg * 16 + i * 4 + 3] = v.w;
        }
    }
    __syncthreads();
    {   // gather transposed, split, 16B stores
        const int n_r = t >> 2, cseg = t & 3;
        unsigned short th[16] __attribute__((aligned(16)));
        unsigned short tlo[16] __attribute__((aligned(16)));
        #pragma unroll
        for (int k = 0; k < 16; ++k)
            split_bf(tl[cseg * 16 + k][n_r], th[k], tlo[k]);
        const size_t base = ((size_t)(b * HW + n0 + n_r)) * CIN + c0 + cseg * 16;
        *(bfrag8*)(xhi + base)     = *(const bfrag8*)(th);
        *(bfrag8*)(xhi + base + 8) = *(const bfrag8*)(th + 8);
        *(bfrag8*)(xlo + base)     = *(const bfrag8*)(tlo);
        *(bfrag8*)(xlo + base + 8) = *(const bfrag8*)(tlo + 8);
    }
}

// K2: fghT[b][n][o] f32 = relu?( sum_c xT[n][c] * w[o][c] + beff[o] )  via split-bf16 MFMA
// Also emits f-block (o0==0) as hi/lo bf16 for k_out's MFMA operands.
__launch_bounds__(256)
__global__ void k_fgh(const unsigned short* __restrict__ xhi, const unsigned short* __restrict__ xlo,
                      const unsigned short* __restrict__ whi_, const unsigned short* __restrict__ wlo_,
                      const float* __restrict__ beff, float* __restrict__ fghT,
                      unsigned short* __restrict__ fhi, unsigned short* __restrict__ flo) {
    __shared__ unsigned short xh[64][72], xl[64][72], wh[64][72], wl[64][72];
    const int n0 = blockIdx.x * 64;
    const int o0 = blockIdx.y * 64;     // 0,64,128
    const int b  = blockIdx.z;
    const int tid = threadIdx.x, l = tid & 63, w = tid >> 6;
    const int wo = w >> 1, wn = w & 1;
    const int lr = l & 15, lk = l >> 4;
    facc4 acc[2][2];
    #pragma unroll
    for (int i = 0; i < 2; ++i)
        #pragma unroll
        for (int j = 0; j < 2; ++j) acc[i][j] = (facc4){0.f, 0.f, 0.f, 0.f};

    const size_t xbase = ((size_t)(b * HW + n0)) * CIN;
    const size_t wbase = (size_t)o0 * CIN;

    for (int kc = 0; kc < 4; ++kc) {
        const int c0 = kc * 64;
        #pragma unroll
        for (int i = 0; i < 2; ++i) {
            int ch = tid + i * 256;
            int row = ch >> 3, cs = ch & 7;
            const size_t xsrc = xbase + (size_t)row * CIN + c0 + cs * 8;
            const size_t wsrc = wbase + (size_t)row * CIN + c0 + cs * 8;
            *(bfrag8*)&xh[row][cs * 8] = *(const bfrag8*)(xhi + xsrc);
            *(bfrag8*)&xl[row][cs * 8] = *(const bfrag8*)(xlo + xsrc);
            *(bfrag8*)&wh[row][cs * 8] = *(const bfrag8*)(whi_ + wsrc);
            *(bfrag8*)&wl[row][cs * 8] = *(const bfrag8*)(wlo_ + wsrc);
        }
        __syncthreads();
        #pragma unroll
        for (int ks = 0; ks < 2; ++ks) {
            bfrag8 ah[2], al[2], bh[2], bl[2];
            #pragma unroll
            for (int s = 0; s < 2; ++s) {
                ah[s] = *(const bfrag8*)&xh[wn * 32 + s * 16 + lr][ks * 32 + lk * 8];
                al[s] = *(const bfrag8*)&xl[wn * 32 + s * 16 + lr][ks * 32 + lk * 8];
                bh[s] = *(const bfrag8*)&wh[wo * 32 + s * 16 + lr][ks * 32 + lk * 8];
                bl[s] = *(const bfrag8*)&wl[wo * 32 + s * 16 + lr][ks * 32 + lk * 8];
            }
            #pragma unroll
            for (int sn = 0; sn < 2; ++sn)
                #pragma unroll
                for (int so = 0; so < 2; ++so) {
                    acc[sn][so] = __builtin_amdgcn_mfma_f32_16x16x32_bf16(ah[sn], bh[so], acc[sn][so], 0, 0, 0);
                    acc[sn][so] = __builtin_amdgcn_mfma_f32_16x16x32_bf16(ah[sn], bl[so], acc[sn][so], 0, 0, 0);
                    acc[sn][so] = __builtin_amdgcn_mfma_f32_16x16x32_bf16(al[sn], bh[so], acc[sn][so], 0, 0, 0);
                }
        }
        __syncthreads();
    }
    // epilogue: bias + relu; f32 store + (f block) hi/lo bf16 store
    const bool rl = (o0 < 128);
    #pragma unroll
    for (int so = 0; so < 2; ++so) {
        const int o = o0 + wo * 32 + so * 16 + lr;
        const float bias = beff[o];
        #pragma unroll
        for (int sn = 0; sn < 2; ++sn)
            #pragma unroll
            for (int r = 0; r < 4; ++r) {
                const int n = n0 + wn * 32 + sn * 16 + lk * 4 + r;
                float v = acc[sn][so][r] + bias;
                if (rl) v = fmaxf(v, 0.0f);
                fghT[((size_t)(b * HW) + n) * O3 + o] = v;
                if (o0 == 0) {
                    unsigned short hi, lo; split_bf(v, hi, lo);
                    fhi[((size_t)(b * HW) + n) * MID + o] = hi;
                    flo[((size_t)(b * HW) + n) * MID + o] = lo;
                }
            }
    }
}

// K3: t[b][c] = sum_n g[n][c] * v0[n]   (128-n chunk per block)
__global__ void k_t(const float* __restrict__ fghT, const float* __restrict__ v0,
                    float* __restrict__ t) {
    __shared__ float red[16][64];
    const int b = blockIdx.y, n0 = blockIdx.x * 128;
    const int tid = threadIdx.x, cq = tid & 15, ng = tid >> 4;
    float a[4] = {0.f, 0.f, 0.f, 0.f};
    for (int it = 0; it < 8; ++it) {
        const int n = n0 + ng + 16 * it;
        float4 gv = *(const float4*)(fghT + ((size_t)(b * HW) + n) * O3 + 64 + cq * 4);
        const float vv = v0[(size_t)b * HW + n];
        a[0] = fmaf(gv.x, vv, a[0]); a[1] = fmaf(gv.y, vv, a[1]);
        a[2] = fmaf(gv.z, vv, a[2]); a[3] = fmaf(gv.w, vv, a[3]);
    }
    #pragma unroll
    for (int i = 0; i < 4; ++i) red[ng][cq * 4 + i] = a[i];
    __syncthreads();
    if (tid < 64) {
        float s = 0.f;
        #pragma unroll
        for (int g = 0; g < 16; ++g) s += red[g][tid];
        atomicAdd(&t[b * MID + tid], s);
    }
}

// K4 (fused): vu[n] = sum_c f[n][c] t[c] (kept in LDS); nsq += |vu|^2;
//             fgvu[r] += sum_n fghT[n][r] * vu[n]    (256-n chunk per block)
__launch_bounds__(256)
__global__ void k_vfg(const float* __restrict__ fghT, const float* __restrict__ t,
                      float* __restrict__ fgvu, float* __restrict__ nsq) {
    __shared__ float ts[64];
    __shared__ float vuls[256];
    __shared__ float red2[8][128];
    __shared__ float rs[4];
    const int b = blockIdx.y, n0 = blockIdx.x * 256;
    const int tid = threadIdx.x;
    if (tid < 64) ts[tid] = t[b * MID + tid];
    __syncthreads();
    // phase 1: vu for this block's 256 n (4 lanes cooperate per n)
    const int nl = tid >> 2, q = tid & 3;
    float mynsq = 0.f;
    for (int ps = 0; ps < 4; ++ps) {
        const int n = n0 + ps * 64 + nl;
        const float* p = fghT + ((size_t)(b * HW) + n) * O3 + q * 16;
        float a = 0.f;
        #pragma unroll
        for (int u = 0; u < 4; ++u) {
            float4 fv = *(const float4*)(p + u * 4);
            a = fmaf(fv.x, ts[q * 16 + u * 4 + 0], a);
            a = fmaf(fv.y, ts[q * 16 + u * 4 + 1], a);
            a = fmaf(fv.z, ts[q * 16 + u * 4 + 2], a);
            a = fmaf(fv.w, ts[q * 16 + u * 4 + 3], a);
        }
        a += __shfl_xor(a, 1);
        a += __shfl_xor(a, 2);
        if (q == 0) { vuls[ps * 64 + nl] = a; mynsq += a * a; }
    }
    {   // nsq reduce (barrier also publishes vuls)
        float s = mynsq;
        #pragma unroll
        for (int off = 32; off > 0; off >>= 1) s += __shfl_down(s, off);
        if ((tid & 63) == 0) rs[tid >> 6] = s;
        __syncthreads();
        if (tid == 0) atomicAdd(&nsq[b], rs[0] + rs[1] + rs[2] + rs[3]);
    }
    // phase 2: fgvu partials
    const int rq = tid & 31, ng2 = tid >> 5;
    float a2[4] = {0.f, 0.f, 0.f, 0.f};
    for (int it = 0; it < 32; ++it) {
        const int ni = ng2 + 8 * it;
        float4 fv = *(const float4*)(fghT + ((size_t)(b * HW) + n0 + ni) * O3 + rq * 4);
        const float vv = vuls[ni];
        a2[0] = fmaf(fv.x, vv, a2[0]); a2[1] = fmaf(fv.y, vv, a2[1]);
        a2[2] = fmaf(fv.z, vv, a2[2]); a2[3] = fmaf(fv.w, vv, a2[3]);
    }
    #pragma unroll
    for (int i = 0; i < 4; ++i) red2[ng2][rq * 4 + i] = a2[i];
    __syncthreads();
    if (tid < 128) {
        float s = 0.f;
        #pragma unroll
        for (int g = 0; g < 8; ++g) s += red2[g][tid];
        atomicAdd(&fgvu[b * 128 + tid], s);
    }
}

// K5: s[b] = (f.vu dot g.vu) / ||vu||^2
__global__ void k_s(const float* __restrict__ fgvu, const float* __restrict__ nsq,
                    float* __restrict__ sval) {
    const int b = blockIdx.x, c = threadIdx.x;  // 64 threads
    float a = fgvu[b * 128 + c] * fgvu[b * 128 + 64 + c];
    #pragma unroll
    for (int off = 32; off > 0; off >>= 1) a += __shfl_down(a, off);
    if (c == 0) sval[b] = a / nsq[b];
}

// K6: split-K partials of M[cp][cc] = sum_n g[n][cp] h[n][cc]   (f32)
__launch_bounds__(256)
__global__ void k_m(const float* __restrict__ fghT, float* __restrict__ mpart) {
    __shared__ float ghls[64][128];   // row=nn; cols 0..63 g, 64..127 h
    const int b = blockIdx.y, kb = blockIdx.x;
    const int tid = threadIdx.x, tc = tid & 15, tcp = tid >> 4;
    float acc[4][4];
    #pragma unroll
    for (int i = 0; i < 4; ++i)
        #pragma unroll
        for (int j = 0; j < 4; ++j) acc[i][j] = 0.f;
    for (int st = 0; st < 2; ++st) {
        const int nb = kb * 128 + st * 64;
        __syncthreads();
        #pragma unroll
        for (int i = 0; i < 8; ++i) {
            int ch = tid + i * 256;
            int row = ch >> 5, cs = ch & 31;
            *(float4*)&ghls[row][cs * 4] =
                *(const float4*)(fghT + ((size_t)(b * HW) + nb + row) * O3 + 64 + cs * 4);
        }
        __syncthreads();
        for (int nn = 0; nn < 64; ++nn) {
            float gv[4], hv[4];
            #pragma unroll
            for (int i = 0; i < 4; ++i) gv[i] = ghls[nn][tcp * 4 + i];
            #pragma unroll
            for (int j = 0; j < 4; ++j) hv[j] = ghls[nn][64 + tc * 4 + j];
            #pragma unroll
            for (int i = 0; i < 4; ++i)
                #pragma unroll
                for (int j = 0; j < 4; ++j) acc[i][j] = fmaf(gv[i], hv[j], acc[i][j]);
        }
    }
    #pragma unroll
    for (int i = 0; i < 4; ++i) {
        float4 v = make_float4(acc[i][0], acc[i][1], acc[i][2], acc[i][3]);
        *(float4*)(mpart + (((size_t)(b * KB_M + kb) * 64 + tcp * 4 + i) * 64 + tc * 4)) = v;
    }
}

// K7: block per (cp, b): Mc[c] = sum_kb mpart[b][kb][cp][c];
//     w2[b][o][cp] = (1/s) * dot(Wv[o][:], Mc)   (hi/lo bf16)
__launch_bounds__(256)
__global__ void k_w2(const float* __restrict__ Wv, const float* __restrict__ mpart,
                     const float* __restrict__ sval,
                     unsigned short* __restrict__ w2hi, unsigned short* __restrict__ w2lo) {
    __shared__ float part[4][64];
    __shared__ float Mc[64];
    const int cp = blockIdx.x, b = blockIdx.y;
    const int tid = threadIdx.x;
    const int c = tid & 63, grp = tid >> 6;   // 4 groups x 8 kb each
    float s = 0.f;
    #pragma unroll
    for (int i = 0; i < 8; ++i) {
        const int kb = grp * 8 + i;
        s += mpart[((size_t)(b * KB_M + kb) * 64 + cp) * 64 + c];
    }
    part[grp][c] = s;
    __syncthreads();
    if (tid < 64) Mc[tid] = part[0][tid] + part[1][tid] + part[2][tid] + part[3][tid];
    __syncthreads();
    const float inv_s = 1.0f / sval[b];
    const int o = tid;   // 0..255
    float a = 0.f;
    #pragma unroll
    for (int u = 0; u < 16; ++u) {
        float4 wv4 = *(const float4*)(Wv + o * MID + u * 4);
        a = fmaf(wv4.x, Mc[u * 4 + 0], a);
        a = fmaf(wv4.y, Mc[u * 4 + 1], a);
        a = fmaf(wv4.z, Mc[u * 4 + 2], a);
        a = fmaf(wv4.w, Mc[u * 4 + 3], a);
    }
    unsigned short hi, lo; split_bf(a * inv_s, hi, lo);
    w2hi[((size_t)(b * CIN) + o) * MID + cp] = hi;
    w2lo[((size_t)(b * CIN) + o) * MID + cp] = lo;
}

// K8: out[b][o][n] = x + bv[o] + sum_cp w2[o][cp] f[n][cp]   via split-bf16 MFMA, D[o][n]
__launch_bounds__(256)
__global__ void k_out(const float* __restrict__ x,
                      const unsigned short* __restrict__ fhi, const unsigned short* __restrict__ flo,
                      const unsigned short* __restrict__ w2hi, const unsigned short* __restrict__ w2lo,
                      const float* __restrict__ bv, float* __restrict__ out) {
    __shared__ unsigned short fh[64][72], fl[64][72], wh[64][72], wl[64][72];
    const int n0 = blockIdx.x * 64;
    const int o0 = blockIdx.y * 64;
    const int b  = blockIdx.z;
    const int tid = threadIdx.x, l = tid & 63, w = tid >> 6;
    const int wo = w >> 1, wn = w & 1;
    const int lr = l & 15, lk = l >> 4;
    #pragma unroll
    for (int i = 0; i < 2; ++i) {
        int ch = tid + i * 256;
        int row = ch >> 3, cs = ch & 7;
        const size_t fsrc = ((size_t)(b * HW) + n0 + row) * MID + cs * 8;
        const size_t wsrc = ((size_t)(b * CIN) + o0 + row) * MID + cs * 8;
        *(bfrag8*)&fh[row][cs * 8] = *(const bfrag8*)(fhi + fsrc);
        *(bfrag8*)&fl[row][cs * 8] = *(const bfrag8*)(flo + fsrc);
        *(bfrag8*)&wh[row][cs * 8] = *(const bfrag8*)(w2hi + wsrc);
        *(bfrag8*)&wl[row][cs * 8] = *(const bfrag8*)(w2lo + wsrc);
    }
    __syncthreads();
    facc4 acc[2][2];   // [so][sn]
    #pragma unroll
    for (int i = 0; i < 2; ++i)
        #pragma unroll
        for (int j = 0; j < 2; ++j) acc[i][j] = (facc4){0.f, 0.f, 0.f, 0.f};
    #pragma unroll
    for (int ks = 0; ks < 2; ++ks) {
        bfrag8 ah[2], al[2], bh[2], bl[2];
        #pragma unroll
        for (int s = 0; s < 2; ++s) {
            ah[s] = *(const bfrag8*)&wh[wo * 32 + s * 16 + lr][ks * 32 + lk * 8];
            al[s] = *(const bfrag8*)&wl[wo * 32 + s * 16 + lr][ks * 32 + lk * 8];
            bh[s] = *(const bfrag8*)&fh[wn * 32 + s * 16 + lr][ks * 32 + lk * 8];
            bl[s] = *(const bfrag8*)&fl[wn * 32 + s * 16 + lr][ks * 32 + lk * 8];
        }
        #pragma unroll
        for (int so = 0; so < 2; ++so)
            #pragma unroll
            for (int sn = 0; sn < 2; ++sn) {
                acc[so][sn] = __builtin_amdgcn_mfma_f32_16x16x32_bf16(ah[so], bh[sn], acc[so][sn], 0, 0, 0);
                acc[so][sn] = __builtin_amdgcn_mfma_f32_16x16x32_bf16(ah[so], bl[sn], acc[so][sn], 0, 0, 0);
                acc[so][sn] = __builtin_amdgcn_mfma_f32_16x16x32_bf16(al[so], bh[sn], acc[so][sn], 0, 0, 0);
            }
    }
    #pragma unroll
    for (int so = 0; so < 2; ++so)
        #pragma unroll
        for (int r = 0; r < 4; ++r) {
            const int o = o0 + wo * 32 + so * 16 + lk * 4 + r;
            const float bias = bv[o];
            #pragma unroll
            for (int sn = 0; sn < 2; ++sn) {
                const int n = n0 + wn * 32 + sn * 16 + lr;
                const size_t idx = ((size_t)(b * CIN) + o) * HW + n;
                out[idx] = x[idx] + bias + acc[so][sn][r];
            }
        }
}

extern "C" void kernel_launch(void* const* d_in, const int* in_sizes, int n_in,
                              void* d_out, int out_size, void* d_ws, size_t ws_size,
                              hipStream_t stream) {
    const float* x   = (const float*)d_in[0];
    const float* Wf  = (const float*)d_in[1];
    const float* bf  = (const float*)d_in[2];
    const float* gaf = (const float*)d_in[3];
    const float* bef = (const float*)d_in[4];
    const float* mef = (const float*)d_in[5];
    const float* vaf = (const float*)d_in[6];
    const float* Wg  = (const float*)d_in[7];
    const float* bg  = (const float*)d_in[8];
    const float* gag = (const float*)d_in[9];
    const float* beg = (const float*)d_in[10];
    const float* meg = (const float*)d_in[11];
    const float* vag = (const float*)d_in[12];
    const float* Wh  = (const float*)d_in[13];
    const float* bh  = (const float*)d_in[14];
    const float* Wv  = (const float*)d_in[15];
    const float* bv  = (const float*)d_in[16];
    const float* v0  = (const float*)d_in[17];
    float* out = (float*)d_out;
    char* ws = (char*)d_ws;

    float*          fghT = (float*)(ws + OFF_FGHT);
    unsigned short* fhi  = (unsigned short*)(ws + OFF_FHI);
    unsigned short* flo  = (unsigned short*)(ws + OFF_FLO);
    unsigned short* xhi  = (unsigned short*)(ws + OFF_XHI);
    unsigned short* xlo  = (unsigned short*)(ws + OFF_XLO);
    unsigned short* whi  = (unsigned short*)(ws + OFF_WHI);
    unsigned short* wlo  = (unsigned short*)(ws + OFF_WLO);
    float*          beff = (float*)(ws + OFF_BEFF);
    unsigned short* w2hi = (unsigned short*)(ws + OFF_W2HI);
    unsigned short* w2lo = (unsigned short*)(ws + OFF_W2LO);
    float*          mpart= (float*)(ws + OFF_MPART);
    float*          tvec = (float*)(ws + OFF_T);
    float*          fgvu = (float*)(ws + OFF_FGVU);
    float*          nsq  = (float*)(ws + OFF_NSQ);
    float*          sval = (float*)(ws + OFF_SVAL);

    // zero atomically-accumulated scratch (t, fgvu, nsq)
    hipMemsetAsync(tvec, 0, 3328, stream);

    k_weff<<<O3, CIN, 0, stream>>>(Wf, bf, gaf, bef, mef, vaf,
                                   Wg, bg, gag, beg, meg, vag,
                                   Wh, bh, whi, wlo, beff);
    k_xt  <<<dim3(HW / 64, CIN / 64, NB), 256, 0, stream>>>(x, xhi, xlo);
    k_fgh <<<dim3(HW / 64, O3 / 64, NB), 256, 0, stream>>>(xhi, xlo, whi, wlo, beff, fghT, fhi, flo);
    k_t   <<<dim3(32, NB), 256, 0, stream>>>(fghT, v0, tvec);
    k_m   <<<dim3(KB_M, NB), 256, 0, stream>>>(fghT, mpart);
    k_vfg <<<dim3(16, NB), 256, 0, stream>>>(fghT, tvec, fgvu, nsq);
    k_s   <<<NB, 64, 0, stream>>>(fgvu, nsq, sval);
    k_w2  <<<dim3(MID, NB), 256, 0, stream>>>(Wv, mpart, sval, w2hi, w2lo);
    k_out <<<dim3(HW / 64, CIN / 64, NB), 256, 0, stream>>>(x, fhi, flo, w2hi, w2lo, bv, out);
}

// Round 7
// 138.271 us; speedup vs baseline: 1.5239x; 1.0839x over previous
//
#include <hip/hip_runtime.h>

// Problem dims
#define NB   4
#define CIN  256
#define MID  64
#define HW   4096

typedef __attribute__((ext_vector_type(8))) short bfrag8;   // 8 bf16 (4 VGPR) MFMA operand
typedef __attribute__((ext_vector_type(4))) float facc4;    // MFMA accumulator

// Workspace layout (bytes), total ~17.3 MB
constexpr size_t OFF_FGHT  = 0;           // [B][4096][128] f32 (f,g; h stays on-chip)
constexpr size_t OFF_FHI   = 8388608;     // [B][4096][64] bf16
constexpr size_t OFF_FLO   = 10485760;    // [B][4096][64] bf16
constexpr size_t OFF_WHI   = 12582912;    // [192][256] bf16
constexpr size_t OFF_WLO   = 12681216;    // [192][256] bf16
constexpr size_t OFF_BEFF  = 12779520;    // [192] f32 (pad 1KB)
constexpr size_t OFF_W2HI  = 12780544;    // [B][256][64] bf16
constexpr size_t OFF_W2LO  = 12911616;    // [B][256][64] bf16
constexpr size_t OFF_MPART = 13042688;    // [B][64 nb][64][64] f32
constexpr size_t OFF_T     = 17236992;    // [B][64] f32   (zeroed)
constexpr size_t OFF_FGVU  = 17238016;    // [B][128] f32  (zeroed)
constexpr size_t OFF_NSQ   = 17240064;    // [B] f32       (zeroed)

__device__ __forceinline__ unsigned short f2bf(float f) {
    union { float f; unsigned u; } v; v.f = f;
    unsigned r = v.u + 0x7FFF + ((v.u >> 16) & 1);  // RNE
    return (unsigned short)(r >> 16);
}
__device__ __forceinline__ float bf2f(unsigned short h) {
    union { unsigned u; float f; } v; v.u = ((unsigned)h) << 16;
    return v.f;
}
__device__ __forceinline__ void split_bf(float v, unsigned short& hi, unsigned short& lo) {
    hi = f2bf(v);
    lo = f2bf(v - bf2f(hi));
}

// K0: fold BN into conv weights -> hi/lo bf16 [o][c]; beff f32
__global__ void k_weff(const float* __restrict__ Wf, const float* __restrict__ bf,
                       const float* __restrict__ gf, const float* __restrict__ btf,
                       const float* __restrict__ mf, const float* __restrict__ vf,
                       const float* __restrict__ Wg, const float* __restrict__ bg,
                       const float* __restrict__ gg, const float* __restrict__ btg,
                       const float* __restrict__ mg, const float* __restrict__ vg,
                       const float* __restrict__ Wh, const float* __restrict__ bh,
                       unsigned short* __restrict__ whi, unsigned short* __restrict__ wlo,
                       float* __restrict__ beff) {
    const int o = blockIdx.x;   // 0..191
    const int c = threadIdx.x;  // 0..255
    float w, sh;
    if (o < 64) {
        float inv = gf[o] * rsqrtf(vf[o] + 1e-5f);
        w  = Wf[o * CIN + c] * inv;
        sh = bf[o] * inv + btf[o] - mf[o] * inv;
    } else if (o < 128) {
        int oo = o - 64;
        float inv = gg[oo] * rsqrtf(vg[oo] + 1e-5f);
        w  = Wg[oo * CIN + c] * inv;
        sh = bg[oo] * inv + btg[oo] - mg[oo] * inv;
    } else {
        int oo = o - 128;
        w  = Wh[oo * CIN + c];
        sh = bh[oo];
    }
    unsigned short hi, lo; split_bf(w, hi, lo);
    whi[o * CIN + c] = hi;
    wlo[o * CIN + c] = lo;
    if (c == 0) beff[o] = sh;
}

// K1 (mega): per block: 64 n x all 192 o.
//  - reads x f32, splits to hi/lo bf16 in LDS (transposed) per-64c chunk
//  - split-bf16 MFMA GEMM -> f,g,h
//  - epilogue: fghT f32 [n][128] (f,g), fhi/flo bf16 (f), and in-LDS g,h ->
//    t-partials (atomicAdd) + M-partials (mpart[b][nb][64][64])
__launch_bounds__(512)
__global__ void k_fgh2(const float* __restrict__ x,
                       const unsigned short* __restrict__ whi_g,
                       const unsigned short* __restrict__ wlo_g,
                       const float* __restrict__ beff,
                       const float* __restrict__ v0,
                       float* __restrict__ fghT,
                       unsigned short* __restrict__ fhi,
                       unsigned short* __restrict__ flo,
                       float* __restrict__ tvec,
                       float* __restrict__ mpart) {
    __shared__ unsigned short xh[64][72], xl[64][72];   // 18.4 KB
    __shared__ char wbuf[2 * 192 * 72 * 2];             // 55.3 KB (wh, wl; reused in epilogue)
    unsigned short (*wh)[72] = (unsigned short(*)[72])wbuf;
    unsigned short (*wl)[72] = (unsigned short(*)[72])(wbuf + 192 * 72 * 2);

    const int nb = blockIdx.x, b = blockIdx.y;
    const int n0 = nb * 64;
    const int tid = threadIdx.x, l = tid & 63, w = tid >> 6;  // 8 waves
    const int wo = w >> 1, wn = w & 1;                        // 4 o-quarters x 2 n-halves
    const int lr = l & 15, lk = l >> 4;
    facc4 acc[2][3];
    #pragma unroll
    for (int i = 0; i < 2; ++i)
        #pragma unroll
        for (int j = 0; j < 3; ++j) acc[i][j] = (facc4){0.f, 0.f, 0.f, 0.f};

    const int cr = tid >> 4, nq = tid & 15;   // x-stage: c-pair, n-quad

    for (int kc = 0; kc < 4; ++kc) {
        const int c0 = kc * 64;
        {   // stage x chunk [64c][64n] f32 -> xh/xl [n][c] (split in-flight)
            const float* xr = x + ((size_t)(b * CIN + c0 + cr * 2)) * HW + n0 + nq * 4;
            float4 va = *(const float4*)xr;
            float4 vb = *(const float4*)(xr + HW);
            #pragma unroll
            for (int i = 0; i < 4; ++i) {
                float fa = (&va.x)[i], fb = (&vb.x)[i];
                unsigned short ha, la, hb, lb;
                split_bf(fa, ha, la);
                split_bf(fb, hb, lb);
                const int n = nq * 4 + i;
                *(unsigned int*)&xh[n][cr * 2] = (unsigned int)ha | ((unsigned int)hb << 16);
                *(unsigned int*)&xl[n][cr * 2] = (unsigned int)la | ((unsigned int)lb << 16);
            }
        }
        {   // stage w chunk [192o][64c]
            #pragma unroll
            for (int k = 0; k < 3; ++k) {
                const int id = tid + k * 512;
                const int orow = id >> 3, cs = id & 7;
                *(bfrag8*)&wh[orow][cs * 8] = *(const bfrag8*)(whi_g + orow * CIN + c0 + cs * 8);
                *(bfrag8*)&wl[orow][cs * 8] = *(const bfrag8*)(wlo_g + orow * CIN + c0 + cs * 8);
            }
        }
        __syncthreads();
        #pragma unroll
        for (int ks = 0; ks < 2; ++ks) {
            bfrag8 ah[2], al[2];
            #pragma unroll
            for (int s = 0; s < 2; ++s) {
                ah[s] = *(const bfrag8*)&xh[wn * 32 + s * 16 + lr][ks * 32 + lk * 8];
                al[s] = *(const bfrag8*)&xl[wn * 32 + s * 16 + lr][ks * 32 + lk * 8];
            }
            #pragma unroll
            for (int so = 0; so < 3; ++so) {
                bfrag8 bh = *(const bfrag8*)&wh[wo * 48 + so * 16 + lr][ks * 32 + lk * 8];
                bfrag8 bl = *(const bfrag8*)&wl[wo * 48 + so * 16 + lr][ks * 32 + lk * 8];
                #pragma unroll
                for (int sn = 0; sn < 2; ++sn) {
                    acc[sn][so] = __builtin_amdgcn_mfma_f32_16x16x32_bf16(ah[sn], bh, acc[sn][so], 0, 0, 0);
                    acc[sn][so] = __builtin_amdgcn_mfma_f32_16x16x32_bf16(ah[sn], bl, acc[sn][so], 0, 0, 0);
                    acc[sn][so] = __builtin_amdgcn_mfma_f32_16x16x32_bf16(al[sn], bh, acc[sn][so], 0, 0, 0);
                }
            }
        }
        __syncthreads();
    }

    // ---- epilogue ----
    float (*mls)[136]  = (float(*)[136])wbuf;            // g,h: [64 n][128 c'] (34.8 KB, aliases wh/wl)
    float (*tred)[64]  = (float(*)[64])(wbuf + 36864);   // 2 KB reduce scratch
    float* v0ls        = (float*)xh;                     // 64 f32 (aliases xh)

    #pragma unroll
    for (int so = 0; so < 3; ++so) {
        const int o = wo * 48 + so * 16 + lr;
        const float bias = beff[o];
        const bool rl = (o < 128);   // relu on f,g only
        #pragma unroll
        for (int sn = 0; sn < 2; ++sn)
            #pragma unroll
            for (int r = 0; r < 4; ++r) {
                const int nn = wn * 32 + sn * 16 + lk * 4 + r;
                const int n = n0 + nn;
                float v = acc[sn][so][r] + bias;
                if (rl) v = fmaxf(v, 0.0f);
                if (o < 128) fghT[((size_t)(b * HW) + n) * 128 + o] = v;
                if (o < 64) {
                    unsigned short hi, lo; split_bf(v, hi, lo);
                    fhi[((size_t)(b * HW) + n) * MID + o] = hi;
                    flo[((size_t)(b * HW) + n) * MID + o] = lo;
                }
                if (o >= 64) mls[nn][o - 64] = v;   // g (relu'd) cols 0..63, h cols 64..127
            }
    }
    if (tid < 64) v0ls[tid] = v0[(size_t)b * HW + n0 + tid];
    __syncthreads();

    {   // t partials: t[c] += sum_n g[n][c] * v0[n]
        const int c = tid & 63, ng = tid >> 6;
        float tp = 0.f;
        #pragma unroll
        for (int i = 0; i < 8; ++i) {
            const int nn = ng * 8 + i;
            tp = fmaf(mls[nn][c], v0ls[nn], tp);
        }
        tred[ng][c] = tp;
    }
    {   // M partials: mpart[b][nb][cp][cc] = sum_n g[n][cp] * h[n][cc]
        const int tcp = tid >> 4, tc = tid & 15;
        const int cp = tcp * 2, cc = tc * 4;
        float macc[2][4];
        #pragma unroll
        for (int i = 0; i < 2; ++i)
            #pragma unroll
            for (int j = 0; j < 4; ++j) macc[i][j] = 0.f;
        for (int nn = 0; nn < 64; ++nn) {
            const float g0 = mls[nn][cp], g1 = mls[nn][cp + 1];
            const float h0 = mls[nn][64 + cc + 0], h1 = mls[nn][64 + cc + 1];
            const float h2 = mls[nn][64 + cc + 2], h3 = mls[nn][64 + cc + 3];
            macc[0][0] = fmaf(g0, h0, macc[0][0]); macc[0][1] = fmaf(g0, h1, macc[0][1]);
            macc[0][2] = fmaf(g0, h2, macc[0][2]); macc[0][3] = fmaf(g0, h3, macc[0][3]);
            macc[1][0] = fmaf(g1, h0, macc[1][0]); macc[1][1] = fmaf(g1, h1, macc[1][1]);
            macc[1][2] = fmaf(g1, h2, macc[1][2]); macc[1][3] = fmaf(g1, h3, macc[1][3]);
        }
        const size_t mpb = ((size_t)(b * 64 + nb) * 64) * 64;
        *(float4*)&mpart[mpb + (size_t)(cp + 0) * 64 + cc] =
            make_float4(macc[0][0], macc[0][1], macc[0][2], macc[0][3]);
        *(float4*)&mpart[mpb + (size_t)(cp + 1) * 64 + cc] =
            make_float4(macc[1][0], macc[1][1], macc[1][2], macc[1][3]);
    }
    __syncthreads();
    if (tid < 64) {
        float s = 0.f;
        #pragma unroll
        for (int g = 0; g < 8; ++g) s += tred[g][tid];
        atomicAdd(&tvec[b * MID + tid], s);
    }
}

// K2 (fused): vu[n] = sum_c f[n][c] t[c] (in LDS); nsq += |vu|^2;
//             fgvu[r] += sum_n fghT[n][r] * vu[n]   (256-n chunk per block)
__launch_bounds__(256)
__global__ void k_vfg(const float* __restrict__ fghT, const float* __restrict__ t,
                      float* __restrict__ fgvu, float* __restrict__ nsq) {
    __shared__ float ts[64];
    __shared__ float vuls[256];
    __shared__ float red2[8][128];
    __shared__ float rs[4];
    const int b = blockIdx.y, n0 = blockIdx.x * 256;
    const int tid = threadIdx.x;
    if (tid < 64) ts[tid] = t[b * MID + tid];
    __syncthreads();
    const int nl = tid >> 2, q = tid & 3;
    float mynsq = 0.f;
    for (int ps = 0; ps < 4; ++ps) {
        const int n = n0 + ps * 64 + nl;
        const float* p = fghT + ((size_t)(b * HW) + n) * 128 + q * 16;
        float a = 0.f;
        #pragma unroll
        for (int u = 0; u < 4; ++u) {
            float4 fv = *(const float4*)(p + u * 4);
            a = fmaf(fv.x, ts[q * 16 + u * 4 + 0], a);
            a = fmaf(fv.y, ts[q * 16 + u * 4 + 1], a);
            a = fmaf(fv.z, ts[q * 16 + u * 4 + 2], a);
            a = fmaf(fv.w, ts[q * 16 + u * 4 + 3], a);
        }
        a += __shfl_xor(a, 1);
        a += __shfl_xor(a, 2);
        if (q == 0) { vuls[ps * 64 + nl] = a; mynsq += a * a; }
    }
    {
        float s = mynsq;
        #pragma unroll
        for (int off = 32; off > 0; off >>= 1) s += __shfl_down(s, off);
        if ((tid & 63) == 0) rs[tid >> 6] = s;
        __syncthreads();
        if (tid == 0) atomicAdd(&nsq[b], rs[0] + rs[1] + rs[2] + rs[3]);
    }
    const int rq = tid & 31, ng2 = tid >> 5;
    float a2[4] = {0.f, 0.f, 0.f, 0.f};
    for (int it = 0; it < 32; ++it) {
        const int ni = ng2 + 8 * it;
        float4 fv = *(const float4*)(fghT + ((size_t)(b * HW) + n0 + ni) * 128 + rq * 4);
        const float vv = vuls[ni];
        a2[0] = fmaf(fv.x, vv, a2[0]); a2[1] = fmaf(fv.y, vv, a2[1]);
        a2[2] = fmaf(fv.z, vv, a2[2]); a2[3] = fmaf(fv.w, vv, a2[3]);
    }
    #pragma unroll
    for (int i = 0; i < 4; ++i) red2[ng2][rq * 4 + i] = a2[i];
    __syncthreads();
    if (tid < 128) {
        float s = 0.f;
        #pragma unroll
        for (int g = 0; g < 8; ++g) s += red2[g][tid];
        atomicAdd(&fgvu[b * 128 + tid], s);
    }
}

// K3 (fused s + w2): per block (8 cp, b): reduce mpart over nb; s = (f.vu).(g.vu)/|vu|^2;
//     w2[b][o][cp] = (1/s) * dot(Wv[o][:], M[cp][:])   (hi/lo bf16, 16B stores)
__launch_bounds__(256)
__global__ void k_w2s(const float* __restrict__ Wv, const float* __restrict__ mpart,
                      const float* __restrict__ fgvu, const float* __restrict__ nsq,
                      unsigned short* __restrict__ w2hi, unsigned short* __restrict__ w2lo) {
    __shared__ float Mc[8][64];
    __shared__ float svs;
    const int cp0 = blockIdx.x * 8, b = blockIdx.y;
    const int tid = threadIdx.x;
    {   // reduce 64 nb-partials for rows cp0..cp0+7
        const int c = tid & 63;
        const int r0 = tid >> 6, r1 = r0 + 4;
        float s0 = 0.f, s1 = 0.f;
        for (int nb = 0; nb < 64; ++nb) {
            const size_t base = ((size_t)(b * 64 + nb) * 64) * 64;
            s0 += mpart[base + (size_t)(cp0 + r0) * 64 + c];
            s1 += mpart[base + (size_t)(cp0 + r1) * 64 + c];
        }
        Mc[r0][c] = s0;
        Mc[r1][c] = s1;
    }
    if (tid < 64) {
        float a = fgvu[b * 128 + tid] * fgvu[b * 128 + 64 + tid];
        #pragma unroll
        for (int off = 32; off > 0; off >>= 1) a += __shfl_down(a, off);
        if (tid == 0) svs = a / nsq[b];
    }
    __syncthreads();
    const float inv_s = 1.0f / svs;
    const int o = tid;
    float wv[64];
    #pragma unroll
    for (int u = 0; u < 16; ++u) {
        float4 w4 = *(const float4*)(Wv + o * MID + u * 4);
        wv[u * 4 + 0] = w4.x; wv[u * 4 + 1] = w4.y; wv[u * 4 + 2] = w4.z; wv[u * 4 + 3] = w4.w;
    }
    unsigned short rh[8] __attribute__((aligned(16)));
    unsigned short rl[8] __attribute__((aligned(16)));
    #pragma unroll
    for (int j = 0; j < 8; ++j) {
        float a = 0.f;
        #pragma unroll
        for (int c = 0; c < 64; ++c) a = fmaf(wv[c], Mc[j][c], a);
        split_bf(a * inv_s, rh[j], rl[j]);
    }
    const size_t base = ((size_t)(b * CIN) + o) * MID + cp0;
    *(bfrag8*)(w2hi + base) = *(const bfrag8*)rh;
    *(bfrag8*)(w2lo + base) = *(const bfrag8*)rl;
}

// K4: out[b][o][n] = x + bv[o] + sum_cp w2[o][cp] f[n][cp]   via split-bf16 MFMA, D[o][n]
__launch_bounds__(256)
__global__ void k_out(const float* __restrict__ x,
                      const unsigned short* __restrict__ fhi, const unsigned short* __restrict__ flo,
                      const unsigned short* __restrict__ w2hi, const unsigned short* __restrict__ w2lo,
                      const float* __restrict__ bv, float* __restrict__ out) {
    __shared__ unsigned short fh[64][72], fl[64][72], wh[64][72], wl[64][72];
    const int n0 = blockIdx.x * 64;
    const int o0 = blockIdx.y * 64;
    const int b  = blockIdx.z;
    const int tid = threadIdx.x, l = tid & 63, w = tid >> 6;
    const int wo = w >> 1, wn = w & 1;
    const int lr = l & 15, lk = l >> 4;
    #pragma unroll
    for (int i = 0; i < 2; ++i) {
        int ch = tid + i * 256;
        int row = ch >> 3, cs = ch & 7;
        const size_t fsrc = ((size_t)(b * HW) + n0 + row) * MID + cs * 8;
        const size_t wsrc = ((size_t)(b * CIN) + o0 + row) * MID + cs * 8;
        *(bfrag8*)&fh[row][cs * 8] = *(const bfrag8*)(fhi + fsrc);
        *(bfrag8*)&fl[row][cs * 8] = *(const bfrag8*)(flo + fsrc);
        *(bfrag8*)&wh[row][cs * 8] = *(const bfrag8*)(w2hi + wsrc);
        *(bfrag8*)&wl[row][cs * 8] = *(const bfrag8*)(w2lo + wsrc);
    }
    __syncthreads();
    facc4 acc[2][2];   // [so][sn]
    #pragma unroll
    for (int i = 0; i < 2; ++i)
        #pragma unroll
        for (int j = 0; j < 2; ++j) acc[i][j] = (facc4){0.f, 0.f, 0.f, 0.f};
    #pragma unroll
    for (int ks = 0; ks < 2; ++ks) {
        bfrag8 ah[2], al[2], bh[2], bl[2];
        #pragma unroll
        for (int s = 0; s < 2; ++s) {
            ah[s] = *(const bfrag8*)&wh[wo * 32 + s * 16 + lr][ks * 32 + lk * 8];
            al[s] = *(const bfrag8*)&wl[wo * 32 + s * 16 + lr][ks * 32 + lk * 8];
            bh[s] = *(const bfrag8*)&fh[wn * 32 + s * 16 + lr][ks * 32 + lk * 8];
            bl[s] = *(const bfrag8*)&fl[wn * 32 + s * 16 + lr][ks * 32 + lk * 8];
        }
        #pragma unroll
        for (int so = 0; so < 2; ++so)
            #pragma unroll
            for (int sn = 0; sn < 2; ++sn) {
                acc[so][sn] = __builtin_amdgcn_mfma_f32_16x16x32_bf16(ah[so], bh[sn], acc[so][sn], 0, 0, 0);
                acc[so][sn] = __builtin_amdgcn_mfma_f32_16x16x32_bf16(ah[so], bl[sn], acc[so][sn], 0, 0, 0);
                acc[so][sn] = __builtin_amdgcn_mfma_f32_16x16x32_bf16(al[so], bh[sn], acc[so][sn], 0, 0, 0);
            }
    }
    #pragma unroll
    for (int so = 0; so < 2; ++so)
        #pragma unroll
        for (int r = 0; r < 4; ++r) {
            const int o = o0 + wo * 32 + so * 16 + lk * 4 + r;
            const float bias = bv[o];
            #pragma unroll
            for (int sn = 0; sn < 2; ++sn) {
                const int n = n0 + wn * 32 + sn * 16 + lr;
                const size_t idx = ((size_t)(b * CIN) + o) * HW + n;
                out[idx] = x[idx] + bias + acc[so][sn][r];
            }
        }
}

extern "C" void kernel_launch(void* const* d_in, const int* in_sizes, int n_in,
                              void* d_out, int out_size, void* d_ws, size_t ws_size,
                              hipStream_t stream) {
    const float* x   = (const float*)d_in[0];
    const float* Wf  = (const float*)d_in[1];
    const float* bf  = (const float*)d_in[2];
    const float* gaf = (const float*)d_in[3];
    const float* bef = (const float*)d_in[4];
    const float* mef = (const float*)d_in[5];
    const float* vaf = (const float*)d_in[6];
    const float* Wg  = (const float*)d_in[7];
    const float* bg  = (const float*)d_in[8];
    const float* gag = (const float*)d_in[9];
    const float* beg = (const float*)d_in[10];
    const float* meg = (const float*)d_in[11];
    const float* vag = (const float*)d_in[12];
    const float* Wh  = (const float*)d_in[13];
    const float* bh  = (const float*)d_in[14];
    const float* Wv  = (const float*)d_in[15];
    const float* bv  = (const float*)d_in[16];
    const float* v0  = (const float*)d_in[17];
    float* out = (float*)d_out;
    char* ws = (char*)d_ws;

    float*          fghT = (float*)(ws + OFF_FGHT);
    unsigned short* fhi  = (unsigned short*)(ws + OFF_FHI);
    unsigned short* flo  = (unsigned short*)(ws + OFF_FLO);
    unsigned short* whi  = (unsigned short*)(ws + OFF_WHI);
    unsigned short* wlo  = (unsigned short*)(ws + OFF_WLO);
    float*          beff = (float*)(ws + OFF_BEFF);
    unsigned short* w2hi = (unsigned short*)(ws + OFF_W2HI);
    unsigned short* w2lo = (unsigned short*)(ws + OFF_W2LO);
    float*          mpart= (float*)(ws + OFF_MPART);
    float*          tvec = (float*)(ws + OFF_T);
    float*          fgvu = (float*)(ws + OFF_FGVU);
    float*          nsq  = (float*)(ws + OFF_NSQ);

    // zero atomically-accumulated scratch (t, fgvu, nsq)
    hipMemsetAsync(tvec, 0, 3328, stream);

    k_weff<<<192, CIN, 0, stream>>>(Wf, bf, gaf, bef, mef, vaf,
                                    Wg, bg, gag, beg, meg, vag,
                                    Wh, bh, whi, wlo, beff);
    k_fgh2<<<dim3(HW / 64, NB), 512, 0, stream>>>(x, whi, wlo, beff, v0,
                                                  fghT, fhi, flo, tvec, mpart);
    k_vfg <<<dim3(16, NB), 256, 0, stream>>>(fghT, tvec, fgvu, nsq);
    k_w2s <<<dim3(8, NB), 256, 0, stream>>>(Wv, mpart, fgvu, nsq, w2hi, w2lo);
    k_out <<<dim3(HW / 64, CIN / 64, NB), 256, 0, stream>>>(x, fhi, flo, w2hi, w2lo, bv, out);
}